// Round 6
// baseline (167.583 us; speedup 1.0000x reference)
//
#include <hip/hip_runtime.h>

typedef unsigned short u16;
typedef unsigned int u32;
typedef unsigned long long u64;
typedef __bf16 bf16x8 __attribute__((ext_vector_type(8)));
typedef float f32x4 __attribute__((ext_vector_type(4)));

union FragAB {
  bf16x8 v;
  u16 u[8];
  u32 w[4];
  u64 d2[2];
};

__device__ __forceinline__ u16 f2bf(float f) {
  u32 u = __builtin_bit_cast(u32, f);
  u += 0x7fffu + ((u >> 16) & 1u);
  return (u16)(u >> 16);
}

__device__ __forceinline__ void gload_lds16(const void* g, void* l) {
  __builtin_amdgcn_global_load_lds((__attribute__((address_space(1))) void*)g,
                                   (__attribute__((address_space(3))) void*)l, 16, 0, 0);
}

// column permutation within each 32-group: fragment for (kg) becomes 16 contiguous bytes
// e = 8*((k&12)>>2) + 4*(k>>4) + (k&3)
__device__ __forceinline__ int permcol(int n) {
  int k = n & 31;
  return (n & ~31) | ((k & 12) << 1) | ((k & 16) >> 2) | (k & 3);
}

// ---------------- fp32 -> bf16, k-permuted (p-layout) ----------------
__global__ __launch_bounds__(256) void conv_perm_kernel(const float* __restrict__ in,
                                                        u16* __restrict__ out, int n4) {
  int i = blockIdx.x * 256 + threadIdx.x;
  if (i >= n4) return;
  float4 v = ((const float4*)in)[i];
  u64 pk = (u64)f2bf(v.x) | ((u64)f2bf(v.y) << 16) | ((u64)f2bf(v.z) << 32) |
           ((u64)f2bf(v.w) << 48);
  int col = (i << 2) & 2047;
  int g = (col >> 2) & 7;
  int ncol = (col & ~31) | ((2 * (g & 3) + (g >> 2)) << 2);
  size_t row = (size_t)(i >> 9);
  *(u64*)&out[row * 2048 + ncol] = pk;
}

// ---------------- transpose + convert (k-permuted), 64x64 tiles ----------------
__global__ __launch_bounds__(256) void tconv_kernel(const float* __restrict__ in,
                                                    u16* __restrict__ out, int K, int N) {
  __shared__ float tile[64][65];
  int col = threadIdx.x & 63;
  int r0 = threadIdx.x >> 6;
  int kb = blockIdx.y * 64, nb = blockIdx.x * 64;
  int pcol = permcol(col);
#pragma unroll
  for (int i = 0; i < 16; i++) {
    int r = r0 + i * 4;
    tile[r][col] = in[(size_t)(kb + r) * N + nb + col];
  }
  __syncthreads();
#pragma unroll
  for (int i = 0; i < 16; i++) {
    int r = r0 + i * 4;
    out[(size_t)(nb + r) * K + kb + pcol] = f2bf(tile[col][r]);
  }
}

// ---------------- merged weight transpose (k-permuted), 64x64 tiles ----------------
// grid (32, 32, 3): z0 = Wq, z1 = Wk, z2 = Wv (z>0 use bx<16 only)
__global__ __launch_bounds__(256) void tconv3_kernel(const float* __restrict__ Wq,
                                                     const float* __restrict__ Wk,
                                                     const float* __restrict__ Wv,
                                                     u16* __restrict__ slab) {
  const int z = blockIdx.z;
  if (z > 0 && blockIdx.x >= 16) return;
  __shared__ float tile[64][65];
  const float* src = (z == 0) ? Wq : (z == 1 ? Wk : Wv);
  const int srcN = (z == 0) ? 2048 : 1024;
  const int dstRowBase = (z == 0) ? 0 : (z == 1 ? 2048 : 3072);
  int col = threadIdx.x & 63;
  int r0 = threadIdx.x >> 6;
  int kb = blockIdx.y * 64, nb = blockIdx.x * 64;
  int pcol = permcol(col);
#pragma unroll
  for (int i = 0; i < 16; i++) {
    int r = r0 + i * 4;
    tile[r][col] = src[(size_t)(kb + r) * srcN + nb + col];
  }
  __syncthreads();
#pragma unroll
  for (int i = 0; i < 16; i++) {
    int r = r0 + i * 4;
    slab[(size_t)(dstRowBase + nb + r) * 2048 + kb + pcol] = f2bf(tile[col][r]);
  }
}

// ---------------- gate: lgt[h][t] = log_sigmoid(off + hs[t]·Wg[:,h]) ----------------
__global__ __launch_bounds__(256) void gate_kernel(const float* __restrict__ hs,
                                                   const float* __restrict__ Wg,
                                                   float* __restrict__ lgt) {
  int lane = threadIdx.x & 63, wid = threadIdx.x >> 6;
  int t = blockIdx.x * 4 + wid;
  float acc[8] = {0.f, 0.f, 0.f, 0.f, 0.f, 0.f, 0.f, 0.f};
  for (int c = lane; c < 2048; c += 64) {
    float x = hs[(size_t)t * 2048 + c];
    float4 w0 = *(const float4*)&Wg[c * 8];
    float4 w1 = *(const float4*)&Wg[c * 8 + 4];
    acc[0] += x * w0.x; acc[1] += x * w0.y; acc[2] += x * w0.z; acc[3] += x * w0.w;
    acc[4] += x * w1.x; acc[5] += x * w1.y; acc[6] += x * w1.z; acc[7] += x * w1.w;
  }
#pragma unroll
  for (int h = 0; h < 8; h++) {
    float v = acc[h];
    for (int m = 1; m < 64; m <<= 1) v += __shfl_xor(v, m, 64);
    if (lane == 0) {
      float x = 6.906768f + v;
      lgt[h * 2048 + t] = -log1pf(__expf(-x));
    }
  }
}

// ---------------- inclusive cumsum over t, per head ----------------
__global__ __launch_bounds__(256) void cumsum_kernel(const float* __restrict__ lgt,
                                                     float* __restrict__ logG) {
  int h = blockIdx.x;
  __shared__ float buf[2048];
  for (int i = threadIdx.x; i < 2048; i += 256) buf[i] = lgt[h * 2048 + i];
  __syncthreads();
  for (int off = 1; off < 2048; off <<= 1) {
    float tmp[8];
#pragma unroll
    for (int j = 0; j < 8; j++) {
      int i = threadIdx.x + j * 256;
      tmp[j] = (i >= off) ? buf[i - off] : 0.f;
    }
    __syncthreads();
#pragma unroll
    for (int j = 0; j < 8; j++) {
      int i = threadIdx.x + j * 256;
      buf[i] += tmp[j];
    }
    __syncthreads();
  }
  for (int i = threadIdx.x; i < 2048; i += 256) logG[h * 2048 + i] = buf[i];
}

// ---------------- bf16 MFMA GEMM: p-layout inputs, b128 frags, 2-phase dbuf ----------------
// MODE 1: bf16 out, permcol for n < permLim; grid 16*NT, XCD-swizzled.
// MODE 2: split-K x2 -> f32 partials (z=0 -> C0, z=1 -> C1); grid 16*NT*2.
template <int MODE, int NT>
__global__ __launch_bounds__(512, 4) void gemm_v2(const u16* __restrict__ A,
                                                  const u16* __restrict__ BT,
                                                  void* __restrict__ C0,
                                                  void* __restrict__ C1,
                                                  int permLim) {
  __shared__ __align__(16) u16 As[2 * 128 * 64];
  __shared__ __align__(16) u16 Bs[2 * 128 * 64];
  constexpr int nwg = 16 * NT * (MODE == 2 ? 2 : 1);
  constexpr int cpx = nwg >> 3;
  const int raw = (int)blockIdx.x;
  const int wg = (raw & 7) * cpx + (raw >> 3);
  int bx, by, z;
  if constexpr (MODE == 2) {
    z = wg & 1;
    int t = wg >> 1;
    by = t >> 4;
    bx = t & 15;
  } else {
    z = 0;
    by = wg >> 4;
    bx = wg & 15;
  }
  const int kBeg = (MODE == 2) ? z * 1024 : 0;
  const int kEnd = (MODE == 2) ? kBeg + 1024 : 2048;
  constexpr int N = NT * 128;

  const int tid = threadIdx.x;
  const int lane = tid & 63, wid = tid >> 6;
  const int m0 = bx * 128, n0 = by * 128;
  const int wr = wid >> 2, wc = wid & 3;
  const int l15 = lane & 15, kg = lane >> 4;

  f32x4 acc[4][2];
#pragma unroll
  for (int i = 0; i < 4; i++)
#pragma unroll
    for (int j = 0; j < 2; j++) acc[i][j] = f32x4{0.f, 0.f, 0.f, 0.f};

  const int c0 = (wid * 2) * 64 + lane;
  const int c1 = c0 + 64;
  const int r0 = c0 >> 3, s0u = (c0 & 7) ^ (r0 & 7);
  const int r1 = c1 >> 3, s1u = (c1 & 7) ^ (r1 & 7);
  const u16* Asrc0 = A + (size_t)(m0 + r0) * 2048 + s0u * 8;
  const u16* Asrc1 = A + (size_t)(m0 + r1) * 2048 + s1u * 8;
  const u16* Bsrc0 = BT + (size_t)(n0 + r0) * 2048 + s0u * 8;
  const u16* Bsrc1 = BT + (size_t)(n0 + r1) * 2048 + s1u * 8;

  auto stage = [&](int buf, int k0) {
    u16* Ad = As + buf * 8192 + (wid * 2) * 512;
    u16* Bd = Bs + buf * 8192 + (wid * 2) * 512;
    gload_lds16(Asrc0 + k0, Ad);
    gload_lds16(Asrc1 + k0, Ad + 512);
    gload_lds16(Bsrc0 + k0, Bd);
    gload_lds16(Bsrc1 + k0, Bd + 512);
  };

  stage(0, kBeg);
  __syncthreads();

  int cur = 0;
  for (int k0 = kBeg; k0 < kEnd; k0 += 64) {
    if (k0 + 64 < kEnd) stage(cur ^ 1, k0 + 64);
    const u16* Ab = As + cur * 8192;
    const u16* Bb = Bs + cur * 8192;
#pragma unroll
    for (int ks = 0; ks < 2; ks++) {
      FragAB af[4], bfr[2];
#pragma unroll
      for (int mt = 0; mt < 4; mt++) {
        int row = wr * 64 + mt * 16 + l15;
        af[mt].v = *(const bf16x8*)&Ab[row * 64 + 8 * ((ks * 4 + kg) ^ (row & 7))];
      }
#pragma unroll
      for (int nt = 0; nt < 2; nt++) {
        int row = wc * 32 + nt * 16 + l15;
        bfr[nt].v = *(const bf16x8*)&Bb[row * 64 + 8 * ((ks * 4 + kg) ^ (row & 7))];
      }
#pragma unroll
      for (int mt = 0; mt < 4; mt++)
#pragma unroll
        for (int nt = 0; nt < 2; nt++)
          acc[mt][nt] = __builtin_amdgcn_mfma_f32_16x16x32_bf16(af[mt].v, bfr[nt].v, acc[mt][nt], 0, 0, 0);
    }
    __syncthreads();
    cur ^= 1;
  }

#pragma unroll
  for (int mt = 0; mt < 4; mt++) {
#pragma unroll
    for (int re = 0; re < 4; re++) {
      int m = m0 + wr * 64 + mt * 16 + kg * 4 + re;
#pragma unroll
      for (int nt = 0; nt < 2; nt++) {
        int n = n0 + wc * 32 + nt * 16 + l15;
        float v = acc[mt][nt][re];
        if constexpr (MODE == 2) {
          float* P = z ? (float*)C1 : (float*)C0;
          P[(size_t)m * N + n] = v;
        } else {
          int nw = (n < permLim) ? permcol(n) : n;
          ((u16*)C0)[(size_t)m * N + nw] = f2bf(v);
        }
      }
    }
  }
}

// ---------------- power attention: Q-tile 128, KV-tile 32, split-K x4, dbuf ----------------
// QKV layout: qkv[t][4096] = [Qperm(2048) | Kperm(1024) | Vlin(1024)]
// grid 1024: XCD-chunked -> (hq, quarter, slot); qt = slot (q<2) else 15-slot (balance)
__global__ __launch_bounds__(256, 3) void power_attn(const u16* __restrict__ QKV,
                                                     const float* __restrict__ logG,
                                                     u16* __restrict__ y0b,
                                                     float* __restrict__ y1p,
                                                     u16* __restrict__ y2b,
                                                     u16* __restrict__ y3b,
                                                     float* __restrict__ npart) {
  __shared__ __align__(16) u16 Ks[2 * 32 * 128];   // 16KB, XOR-swizzled (16B units)
  __shared__ __align__(16) u16 Vt[2 * 128 * 40];   // 20KB, V^T s-permuted, pad 40
  __shared__ float eS[2 * 32];

  const int raw = (int)blockIdx.x;
  const int orig = (raw & 7) * 128 + (raw >> 3);   // XCD x owns hk = x
  const int hq = orig >> 6;
  const int j_ = orig & 63;
  const int quarter = j_ >> 4;
  const int slot = j_ & 15;
  const int qt = (quarter < 2) ? slot : (15 - slot);
  const int hk = hq >> 1;
  const int t0 = qt * 128;

  const int tid = threadIdx.x, lane = tid & 63, wid = tid >> 6;
  const int l15 = lane & 15, kg = lane >> 4;
  const int l7 = l15 & 7;
  const int s4 = tid & 15, dgrp = tid >> 4;

  const u16* Kbase = QKV + 2048 + hk * 128;
  const u16* Vbase = QKV + 3072 + hk * 128 + dgrp * 8;
  const float* lgh = logG + hk * 2048;

  FragAB qf[2][4];
  float celg[2];
  int myT[2];
  const float scale2 = 0.0078125f;  // 1/128
#pragma unroll
  for (int cg = 0; cg < 2; cg++) {
    myT[cg] = t0 + wid * 16 + cg * 64 + l15;
    const u16* qrow = QKV + (size_t)myT[cg] * 4096 + hq * 128;
#pragma unroll
    for (int ks = 0; ks < 4; ks++) qf[cg][ks].v = *(const bf16x8*)(qrow + ks * 32 + kg * 8);
    celg[cg] = scale2 * __expf(lgh[myT[cg]]);
  }

  f32x4 yacc[8][2];
#pragma unroll
  for (int i = 0; i < 8; i++)
#pragma unroll
    for (int c = 0; c < 2; c++) yacc[i][c] = f32x4{0.f, 0.f, 0.f, 0.f};
  float nacc[2] = {0.f, 0.f};

  const int itBeg = quarter * (qt + 1);
  const int itEnd = itBeg + (qt + 1);

  auto stageK = [&](int s0, int bb) {
#pragma unroll
    for (int c = 0; c < 2; c++) {
      int ch = (wid * 2 + c) * 64 + lane;
      int row = ch >> 4, du = ch & 15;
      int su = du ^ (row & 7);
      gload_lds16(Kbase + (size_t)(s0 + row) * 4096 + su * 8, &Ks[bb * 4096 + (wid * 2 + c) * 512]);
    }
  };
  auto loadV = [&](int s0, uint4* vr) {
    vr[0] = *(const uint4*)(Vbase + (size_t)(s0 + 2 * s4) * 4096);
    vr[1] = *(const uint4*)(Vbase + (size_t)(s0 + 2 * s4 + 1) * 4096);
  };
  auto writeV = [&](int bb, const uint4* vr) {
    u16* vd = &Vt[bb * 5120];
    const u32* w0 = (const u32*)&vr[0];
    const u32* w1 = (const u32*)&vr[1];
    // s = 2*s4 -> permcol position e (s and s+1 are adjacent: e, e+1)
    int e = 8 * ((s4 >> 1) & 3) + 4 * (s4 >> 3) + 2 * (s4 & 1);
#pragma unroll
    for (int i = 0; i < 8; i++) {
      u32 sel = (i & 1) ? 0x07060302u : 0x05040100u;
      u32 val = __builtin_amdgcn_perm(w1[i >> 1], w0[i >> 1], sel);
      int d = dgrp * 8 + i;
      *(u32*)&vd[d * 40 + e] = val;
    }
  };

  {  // prologue
    uint4 vr[2];
    stageK(itBeg * 32, 0);
    loadV(itBeg * 32, vr);
    float ee = (tid < 32) ? lgh[itBeg * 32 + tid] : 0.f;
    writeV(0, vr);
    if (tid < 32) eS[tid] = __expf(-ee);
  }
  __syncthreads();

  for (int it = itBeg; it < itEnd; it++) {
    const int cur = (it - itBeg) & 1;
    const int s0 = it * 32;
    const bool hasNext = (it + 1 < itEnd);
    uint4 vr[2];
    float ee = 0.f;
    if (hasNext) {  // issue next tile's loads early (hidden under compute)
      stageK(s0 + 32, cur ^ 1);
      loadV(s0 + 32, vr);
      if (tid < 32) ee = lgh[s0 + 32 + tid];
    }

    // ---- S^T = K · Q^T on buf[cur] ----
    const u16* kb = &Ks[cur * 4096];
    f32x4 sacc[2][2];
#pragma unroll
    for (int mt = 0; mt < 2; mt++)
#pragma unroll
      for (int cg = 0; cg < 2; cg++) sacc[mt][cg] = f32x4{0.f, 0.f, 0.f, 0.f};
    __builtin_amdgcn_s_setprio(1);
#pragma unroll
    for (int ks = 0; ks < 4; ks++) {
#pragma unroll
      for (int mt = 0; mt < 2; mt++) {
        FragAB af;
        af.v = *(const bf16x8*)&kb[(mt * 16 + l15) * 128 + 8 * ((4 * ks + kg) ^ l7)];
        sacc[mt][0] = __builtin_amdgcn_mfma_f32_16x16x32_bf16(af.v, qf[0][ks].v, sacc[mt][0], 0, 0, 0);
        sacc[mt][1] = __builtin_amdgcn_mfma_f32_16x16x32_bf16(af.v, qf[1][ks].v, sacc[mt][1], 0, 0, 0);
      }
    }
    __builtin_amdgcn_s_setprio(0);

    // ---- P = (qk)^2/128 * exp(lgT - lgS); causal mask near diagonal ----
    FragAB pa[2];
    const bool need_mask = (it >= 4 * qt);
#pragma unroll
    for (int mt = 0; mt < 2; mt++) {
      f32x4 ev = *(const f32x4*)&eS[cur * 32 + mt * 16 + kg * 4];
#pragma unroll
      for (int cg = 0; cg < 2; cg++) {
#pragma unroll
        for (int r = 0; r < 4; r++) {
          float x = sacc[mt][cg][r];
          float p = x * x * celg[cg] * ev[r];
          if (need_mask) {
            int s = s0 + mt * 16 + kg * 4 + r;
            p = (s <= myT[cg]) ? p : 0.f;
          }
          nacc[cg] += p;
          pa[cg].u[mt * 4 + r] = f2bf(p);
        }
      }
    }

    // ---- Y += P · V (single K=32 step) ----
    const u16* vb = &Vt[cur * 5120];
    __builtin_amdgcn_s_setprio(1);
#pragma unroll
    for (int nt = 0; nt < 8; nt++) {
      FragAB bfv;
      bfv.v = *(const bf16x8*)&vb[(nt * 16 + l15) * 40 + 8 * kg];
      yacc[nt][0] = __builtin_amdgcn_mfma_f32_16x16x32_bf16(pa[0].v, bfv.v, yacc[nt][0], 0, 0, 0);
      yacc[nt][1] = __builtin_amdgcn_mfma_f32_16x16x32_bf16(pa[1].v, bfv.v, yacc[nt][1], 0, 0, 0);
    }
    __builtin_amdgcn_s_setprio(0);

    if (hasNext) {
      writeV(cur ^ 1, vr);
      if (tid < 32) eS[(cur ^ 1) * 32 + tid] = __expf(-ee);
    }
    __syncthreads();
  }

  // ---- epilogue: unnormalized partials + per-row norm partial ----
  float* np = npart + quarter * (16 * 2048);
#pragma unroll
  for (int cg = 0; cg < 2; cg++) {
    float nf = nacc[cg];
    nf += __shfl_xor(nf, 16, 64);
    nf += __shfl_xor(nf, 32, 64);
    if (lane < 16) np[hq * 2048 + t0 + wid * 16 + cg * 64 + lane] = nf;
#pragma unroll
    for (int re = 0; re < 4; re++) {
      int trow = t0 + wid * 16 + cg * 64 + kg * 4 + re;
      size_t base = (size_t)trow * 2048 + hq * 128;
      if (quarter == 1) {
#pragma unroll
        for (int nt = 0; nt < 8; nt++) y1p[base + nt * 16 + l15] = yacc[nt][cg][re];
      } else {
        u16* yb = (quarter == 0) ? y0b : (quarter == 2 ? y2b : y3b);
#pragma unroll
        for (int nt = 0; nt < 8; nt++) yb[base + nt * 16 + l15] = f2bf(yacc[nt][cg][re]);
      }
    }
  }
}

// ---------------- combine 4 attention partials + normalize -> bf16 (p-layout) ----------------
__global__ __launch_bounds__(256) void combine_kernel(const u16* __restrict__ y0b,
                                                      const float* __restrict__ y1,
                                                      const u16* __restrict__ y2b,
                                                      const u16* __restrict__ y3b,
                                                      const float* __restrict__ npart,
                                                      u16* __restrict__ yb) {
  int i = blockIdx.x * 256 + threadIdx.x;
  int e0 = i << 2;
  int t = e0 >> 11;
  int hq = (e0 >> 7) & 15;
  int nidx = hq * 2048 + t;
  float nn = npart[nidx] + npart[32768 + nidx] + npart[65536 + nidx] + npart[98304 + nidx] + 1e-6f;
  float inv = 1.0f / nn;
  u64 a0 = *(const u64*)&y0b[e0];
  float4 b = ((const float4*)y1)[i];
  u64 a2 = *(const u64*)&y2b[e0];
  u64 a3 = *(const u64*)&y3b[e0];
  float r[4];
#pragma unroll
  for (int j = 0; j < 4; j++) {
    float v0 = __builtin_bit_cast(float, (u32)((a0 >> (16 * j)) & 0xffffu) << 16);
    float v2 = __builtin_bit_cast(float, (u32)((a2 >> (16 * j)) & 0xffffu) << 16);
    float v3 = __builtin_bit_cast(float, (u32)((a3 >> (16 * j)) & 0xffffu) << 16);
    float bj = (j == 0) ? b.x : (j == 1) ? b.y : (j == 2) ? b.z : b.w;
    r[j] = (v0 + bj + v2 + v3) * inv;
  }
  u64 pk = (u64)f2bf(r[0]) | ((u64)f2bf(r[1]) << 16) | ((u64)f2bf(r[2]) << 32) |
           ((u64)f2bf(r[3]) << 48);
  int col = e0 & 2047;
  int g = (col >> 2) & 7;
  int ncol = (col & ~31) | ((2 * (g & 3) + (g >> 2)) << 2);
  *(u64*)&yb[(size_t)t * 2048 + ncol] = pk;
}

// ---------------- combine out-GEMM split-K partials + bias (in place on d_out) ----------------
__global__ __launch_bounds__(256) void combine2_kernel(const float* __restrict__ p0,
                                                       float* __restrict__ out,
                                                       const float* __restrict__ bias) {
  int i = blockIdx.x * 256 + threadIdx.x;
  int col = (i << 2) & 2047;
  float4 a = ((const float4*)p0)[i];
  float4 b = ((const float4*)out)[i];
  float4 bb = *(const float4*)&bias[col];
  float4 r;
  r.x = a.x + b.x + bb.x;
  r.y = a.y + b.y + bb.y;
  r.z = a.z + b.z + bb.z;
  r.w = a.w + b.w + bb.w;
  ((float4*)out)[i] = r;
}

// ---------------- launch ----------------
extern "C" void kernel_launch(void* const* d_in, const int* in_sizes, int n_in,
                              void* d_out, int out_size, void* d_ws, size_t ws_size,
                              hipStream_t stream) {
  (void)in_sizes; (void)n_in; (void)out_size; (void)ws_size;
  const float* hs = (const float*)d_in[0];
  const float* Wq = (const float*)d_in[1];
  const float* Wk = (const float*)d_in[2];
  const float* Wv = (const float*)d_in[3];
  const float* Wg = (const float*)d_in[4];
  const float* Wc = (const float*)d_in[5];
  const float* bc = (const float*)d_in[6];
  float* out = (float*)d_out;

  char* ws = (char*)d_ws;
  const size_t MB = 1024 * 1024;
  // 0-16MB: slab [WqT|WkT|WvT] p-layout; 0-8MB reused for WcT after qkv GEMM
  // 8-16MB (dead after qkv GEMM): lgt, logG, npart
  // 16-24MB: hs_bf (dead after qkv GEMM) -> y3b (attn q3, bf16)
  // 24-40MB: qkv_bf (dead after attn) -> y_bf (combine output, 24-32MB)
  // 40-48MB: y0b (q0 bf16); 48-56MB: y2b (q2 bf16); 40-56MB reused as f32 out-GEMM partial
  u16* slab   = (u16*)(ws);
  float* lgt  = (float*)(ws + 8 * MB);
  float* logG = (float*)(ws + 8 * MB + 65536);
  float* npart = (float*)(ws + 8 * MB + 131072);  // 512KB (4 quarters x 16 x 2048)
  u16* hs_bf  = (u16*)(ws + 16 * MB);
  u16* y3b    = (u16*)(ws + 16 * MB);
  u16* qkv_bf = (u16*)(ws + 24 * MB);
  u16* y_bf   = (u16*)(ws + 24 * MB);
  u16* y0b    = (u16*)(ws + 40 * MB);
  u16* y2b    = (u16*)(ws + 48 * MB);
  float* y0p  = (float*)(ws + 40 * MB);
  float* y1p = out;
  u16* WcT = slab;

  conv_perm_kernel<<<4096, 256, 0, stream>>>(hs, hs_bf, 2048 * 2048 / 4);
  tconv3_kernel<<<dim3(32, 32, 3), 256, 0, stream>>>(Wq, Wk, Wv, slab);

  // merged QKV GEMM: [2048 x 4096] = hs_bf @ slab^T
  gemm_v2<1, 32><<<512, 512, 0, stream>>>(hs_bf, slab, qkv_bf, nullptr, 3072);

  gate_kernel<<<512, 256, 0, stream>>>(hs, Wg, lgt);
  cumsum_kernel<<<8, 256, 0, stream>>>(lgt, logG);

  tconv_kernel<<<dim3(32, 32), 256, 0, stream>>>(Wc, WcT, 2048, 2048);

  power_attn<<<dim3(1024), 256, 0, stream>>>(qkv_bf, logG, y0b, y1p, y2b, y3b, npart);
  combine_kernel<<<4096, 256, 0, stream>>>(y0b, y1p, y2b, y3b, npart, y_bf);

  // out GEMM split-K x2: partial0 -> y0p, partial1 -> d_out; then add + bias
  gemm_v2<2, 16><<<512, 512, 0, stream>>>(y_bf, WcT, y0p, out, 0);
  combine2_kernel<<<4096, 256, 0, stream>>>(y0p, out, bc);
}